// Round 7
// baseline (96.777 us; speedup 1.0000x reference)
//
#include <hip/hip_runtime.h>

#define CIN  64
#define COUT 64
#define KVOL 27

typedef __attribute__((ext_vector_type(8))) short bf16x8;
typedef __attribute__((ext_vector_type(4))) float f32x4;

union U4H8 { uint4 u; bf16x8 h; };

static __device__ __forceinline__ unsigned short f2bf(float x) {
    union { float f; unsigned int u; } v; v.f = x;
    return (unsigned short)((v.u + 0x7FFFu + ((v.u >> 16) & 1u)) >> 16);  // RNE
}

// Re-pack weight[27][64][64] fp32 -> bf16 B-fragment order:
// entry e = (k*8 + kh*4 + ntl)*64 + lane holds 8 bf16 =
//   W[k][32*kh + (lane>>4)*8 + j][16*ntl + (lane&15)]
__global__ __launch_bounds__(256) void pack_w(const float* __restrict__ W,
                                              unsigned short* __restrict__ wf) {
    int t = blockIdx.x * 256 + threadIdx.x;
    if (t >= KVOL * 8 * 64) return;
    int lane  = t & 63;
    int frag  = (t >> 6) & 7;
    int k     = t >> 9;
    int kh    = frag >> 2, nt = frag & 3;
    int col   = nt * 16 + (lane & 15);
    int kbase = kh * 32 + (lane >> 4) * 8;
    const float* src = W + (size_t)k * (CIN * COUT) + (size_t)kbase * COUT + col;
    unsigned int pk[4];
    #pragma unroll
    for (int j = 0; j < 4; ++j) {
        unsigned int lo = f2bf(src[(2 * j) * COUT]);
        unsigned int hi = f2bf(src[(2 * j + 1) * COUT]);
        pk[j] = lo | (hi << 16);
    }
    *reinterpret_cast<uint4*>(wf + (size_t)t * 8) = make_uint4(pk[0], pk[1], pk[2], pk[3]);
}

// feats fp32 [N][64] -> bf16 [N+1][64] (row N = zeros). One thread = 8 elems.
__global__ __launch_bounds__(256) void cvt_feats(const float* __restrict__ f,
                                                 uint4* __restrict__ o, int total8) {
    int t = blockIdx.x * 256 + threadIdx.x;
    if (t < total8) {
        const float4* p = reinterpret_cast<const float4*>(f) + 2 * (size_t)t;
        float4 a = p[0], b = p[1];
        unsigned int u0 = (unsigned int)f2bf(a.x) | ((unsigned int)f2bf(a.y) << 16);
        unsigned int u1 = (unsigned int)f2bf(a.z) | ((unsigned int)f2bf(a.w) << 16);
        unsigned int u2 = (unsigned int)f2bf(b.x) | ((unsigned int)f2bf(b.y) << 16);
        unsigned int u3 = (unsigned int)f2bf(b.z) | ((unsigned int)f2bf(b.w) << 16);
        o[t] = make_uint4(u0, u1, u2, u3);
    } else if (t < total8 + 8) {
        o[t] = make_uint4(0u, 0u, 0u, 0u);   // zero row at index N
    }
}

// Main: 2 waves/block, 64 rows/wave (4 M-tiles x full 64 cols), software
// pipeline protected by RAW s_barrier (no vmcnt drain). XCD-aware bijective
// block swizzle: each XCD owns a contiguous 16K-row chunk -> gather working
// set (~2 MB bf16 feats) fits its private 4 MB L2.
__global__ __launch_bounds__(128) void spconv_mfma64(
    const char* __restrict__ fbf,          // (n+1) rows x 128 B bf16
    const uint4* __restrict__ wf4,
    const float* __restrict__ bias,
    const int*   __restrict__ in_idx,
    const float* __restrict__ mask,
    float* __restrict__ out, int n)
{
    const int tid  = threadIdx.x;
    const int lane = tid & 63;
    const int wv   = tid >> 6;
    const int rloc = lane & 15;
    const int grp  = lane >> 4;

    // T1: bijective XCD swizzle (nwg % 8 == 0 for n=262144)
    const int nwg = gridDim.x;
    int bid = blockIdx.x;
    if ((nwg & 7) == 0) {
        const int chunk = nwg >> 3;
        bid = (blockIdx.x & 7) * chunk + (blockIdx.x >> 3);
    }
    const int row0 = bid * 128 + wv * 64;

    __shared__ uint4 lds_w[2][512];        // double-buffered B-fragments, 16 KB

    f32x4 acc[4][4];
    #pragma unroll
    for (int nt = 0; nt < 4; ++nt) {
        float b = bias[nt * 16 + rloc];
        f32x4 v = {b, b, b, b};
        acc[0][nt] = v; acc[1][nt] = v; acc[2][nt] = v; acc[3][nt] = v;
    }

    int rowt[4];
    #pragma unroll
    for (int t = 0; t < 4; ++t) rowt[t] = row0 + 16 * t + rloc;

    const unsigned zoff = (unsigned)n * 128u;

    // ---- prologue ----
    int tmpi[4]; float tmpm[4];
    #pragma unroll
    for (int t = 0; t < 4; ++t) { tmpi[t] = in_idx[rowt[t]]; tmpm[t] = mask[rowt[t]]; }

    int idxb[2][4]; float mskb[2][4];
    #pragma unroll
    for (int t = 0; t < 4; ++t) {                       // idx(1) -> buf 1
        idxb[1][t] = in_idx[(size_t)n + rowt[t]];
        mskb[1][t] = mask[(size_t)n + rowt[t]];
    }

    // stage w(0) into LDS (full drain ONCE here is fine)
    lds_w[0][tid]       = wf4[tid];
    lds_w[0][tid + 128] = wf4[tid + 128];
    lds_w[0][tid + 256] = wf4[tid + 256];
    lds_w[0][tid + 384] = wf4[tid + 384];
    __syncthreads();

    // issue A(0) gathers + idx(2) AFTER the drain so they fly into iter 0
    U4H8 a[2][4][2];
    #pragma unroll
    for (int t = 0; t < 4; ++t) {
        unsigned o = (tmpm[t] != 0.0f) ? (unsigned)tmpi[t] * 128u : zoff;
        const uint4* p = reinterpret_cast<const uint4*>(fbf + o) + grp;
        a[0][t][0].u = p[0];
        a[0][t][1].u = p[4];
    }
    #pragma unroll
    for (int t = 0; t < 4; ++t) {                       // idx(2) -> buf 0
        idxb[0][t] = in_idx[(size_t)2 * n + rowt[t]];
        mskb[0][t] = mask[(size_t)2 * n + rowt[t]];
    }

    #pragma unroll
    for (int k = 0; k < KVOL; ++k) {
        const int cur = k & 1;
        const int nxt = cur ^ 1;
        const int par = (k + 1) & 1;       // idx buffer holding idx(k+1)

        // 1. weight prefetch for k+1 — issued FIRST (oldest): the ds_write's
        //    counted vmcnt wait then leaves the younger A-gathers in flight.
        uint4 w0, w1, w2, w3;
        if (k + 1 < KVOL) {
            const uint4* s = wf4 + (size_t)(k + 1) * 512;
            w0 = s[tid]; w1 = s[tid + 128]; w2 = s[tid + 256]; w3 = s[tid + 384];
        }

        // 2. A-gathers for k+1 (idx loaded 2 iters ago)
        if (k + 1 < KVOL) {
            #pragma unroll
            for (int t = 0; t < 4; ++t) {
                unsigned o = (mskb[par][t] != 0.0f) ? (unsigned)idxb[par][t] * 128u : zoff;
                const uint4* p = reinterpret_cast<const uint4*>(fbf + o) + grp;
                a[nxt][t][0].u = p[0];
                a[nxt][t][1].u = p[4];
            }
        }

        // 3. idx/mask for k+3 into the buffer just consumed
        if (k + 3 < KVOL) {
            const size_t kb = (size_t)(k + 3) * n;
            #pragma unroll
            for (int t = 0; t < 4; ++t) {
                idxb[par][t] = in_idx[kb + rowt[t]];
                mskb[par][t] = mask[kb + rowt[t]];
            }
        }

        // 4. B fragments from LDS
        U4H8 bf[2][4];
        #pragma unroll
        for (int kh = 0; kh < 2; ++kh)
            #pragma unroll
            for (int ntl = 0; ntl < 4; ++ntl)
                bf[kh][ntl].u = lds_w[cur][(kh * 4 + ntl) * 64 + lane];

        // 5. 32 MFMAs on fragments gathered last iteration
        #pragma unroll
        for (int t = 0; t < 4; ++t)
            #pragma unroll
            for (int ntl = 0; ntl < 4; ++ntl) {
                acc[t][ntl] = __builtin_amdgcn_mfma_f32_16x16x32_bf16(a[cur][t][0].h, bf[0][ntl].h, acc[t][ntl], 0, 0, 0);
                acc[t][ntl] = __builtin_amdgcn_mfma_f32_16x16x32_bf16(a[cur][t][1].h, bf[1][ntl].h, acc[t][ntl], 0, 0, 0);
            }

        // 6. publish next weight tile; RAW barrier (no vmcnt drain!)
        if (k + 1 < KVOL) {
            lds_w[nxt][tid]       = w0;
            lds_w[nxt][tid + 128] = w1;
            lds_w[nxt][tid + 256] = w2;
            lds_w[nxt][tid + 384] = w3;
            asm volatile("s_waitcnt lgkmcnt(0)" ::: "memory");
            __builtin_amdgcn_s_barrier();
        }
    }

    // C/D layout: col = lane&15, row = grp*4 + reg
    #pragma unroll
    for (int t = 0; t < 4; ++t)
        #pragma unroll
        for (int ntl = 0; ntl < 4; ++ntl)
            #pragma unroll
            for (int r = 0; r < 4; ++r) {
                int orow = row0 + 16 * t + grp * 4 + r;
                out[(size_t)orow * COUT + ntl * 16 + rloc] = acc[t][ntl][r];
            }
}

// ---- fallback (round-2 kernel): fp32 gather + in-loop cvt, used if ws too small ----
static __device__ __forceinline__ bf16x8 cvt8(float4 a, float4 b, float m) {
    bf16x8 r;
    r[0] = (short)f2bf(a.x * m); r[1] = (short)f2bf(a.y * m);
    r[2] = (short)f2bf(a.z * m); r[3] = (short)f2bf(a.w * m);
    r[4] = (short)f2bf(b.x * m); r[5] = (short)f2bf(b.y * m);
    r[6] = (short)f2bf(b.z * m); r[7] = (short)f2bf(b.w * m);
    return r;
}

__global__ __launch_bounds__(256) void spconv_mfma_f32(
    const float* __restrict__ feats,
    const unsigned short* __restrict__ wf,
    const float* __restrict__ bias,
    const int*   __restrict__ in_idx,
    const float* __restrict__ mask,
    float* __restrict__ out, int n)
{
    const int tid  = threadIdx.x;
    const int lane = tid & 63;
    const int wv   = tid >> 6;
    const int rloc = lane & 15;
    const int grp  = lane >> 4;
    const int row0 = blockIdx.x * 128 + wv * 32;

    __shared__ uint4 lds_w[2][512];

    f32x4 acc[2][4];
    #pragma unroll
    for (int nt = 0; nt < 4; ++nt) {
        float b = bias[nt * 16 + rloc];
        f32x4 v = {b, b, b, b};
        acc[0][nt] = v; acc[1][nt] = v;
    }

    const uint4* wf4 = reinterpret_cast<const uint4*>(wf);
    lds_w[0][tid]       = wf4[tid];
    lds_w[0][tid + 256] = wf4[tid + 256];
    __syncthreads();

    const int rowA = row0 + rloc;
    const int rowB = rowA + 16;

    for (int koff = 0; koff < KVOL; ++koff) {
        const int cur = koff & 1;
        uint4 w0, w1;
        const bool pf = (koff + 1 < KVOL);
        if (pf) {
            const uint4* s = wf4 + (size_t)(koff + 1) * 512;
            w0 = s[tid]; w1 = s[tid + 256];
        }

        const size_t kb = (size_t)koff * n;
        const int   idxA = in_idx[kb + rowA];
        const float mA   = mask[kb + rowA];
        const int   idxB = in_idx[kb + rowB];
        const float mB   = mask[kb + rowB];

        const float4* fA = reinterpret_cast<const float4*>(feats + (size_t)idxA * CIN + grp * 8);
        const float4* fB = reinterpret_cast<const float4*>(feats + (size_t)idxB * CIN + grp * 8);
        float4 a0 = fA[0], a1 = fA[1], a2 = fA[8], a3 = fA[9];
        float4 c0 = fB[0], c1 = fB[1], c2 = fB[8], c3 = fB[9];

        bf16x8 aA0 = cvt8(a0, a1, mA), aA1 = cvt8(a2, a3, mA);
        bf16x8 aB0 = cvt8(c0, c1, mB), aB1 = cvt8(c2, c3, mB);

        U4H8 bf[2][4];
        #pragma unroll
        for (int kh = 0; kh < 2; ++kh)
            #pragma unroll
            for (int nt = 0; nt < 4; ++nt)
                bf[kh][nt].u = lds_w[cur][(kh * 4 + nt) * 64 + lane];

        #pragma unroll
        for (int nt = 0; nt < 4; ++nt) {
            acc[0][nt] = __builtin_amdgcn_mfma_f32_16x16x32_bf16(aA0, bf[0][nt].h, acc[0][nt], 0, 0, 0);
            acc[0][nt] = __builtin_amdgcn_mfma_f32_16x16x32_bf16(aA1, bf[1][nt].h, acc[0][nt], 0, 0, 0);
            acc[1][nt] = __builtin_amdgcn_mfma_f32_16x16x32_bf16(aB0, bf[0][nt].h, acc[1][nt], 0, 0, 0);
            acc[1][nt] = __builtin_amdgcn_mfma_f32_16x16x32_bf16(aB1, bf[1][nt].h, acc[1][nt], 0, 0, 0);
        }

        if (pf) {
            lds_w[cur ^ 1][tid]       = w0;
            lds_w[cur ^ 1][tid + 256] = w1;
        }
        __syncthreads();
    }

    #pragma unroll
    for (int t = 0; t < 2; ++t)
        #pragma unroll
        for (int nt = 0; nt < 4; ++nt)
            #pragma unroll
            for (int r = 0; r < 4; ++r) {
                int orow = row0 + t * 16 + grp * 4 + r;
                out[(size_t)orow * COUT + nt * 16 + rloc] = acc[t][nt][r];
            }
}

extern "C" void kernel_launch(void* const* d_in, const int* in_sizes, int n_in,
                              void* d_out, int out_size, void* d_ws, size_t ws_size,
                              hipStream_t stream)
{
    const float* feats  = (const float*)d_in[0];
    const float* weight = (const float*)d_in[1];
    const float* bias   = (const float*)d_in[2];
    const int*   in_idx = (const int*)  d_in[3];
    // d_in[4] = out_idx (unused: out_idx[k][i] == i where mask==1)
    const float* mask   = (const float*)d_in[5];
    float* out = (float*)d_out;

    const int n = in_sizes[0] / CIN;  // 262144

    const size_t WF_BYTES  = (size_t)KVOL * 8 * 64 * 16;          // 221184
    const size_t FBF_BYTES = (size_t)(n + 1) * CIN * 2;           // ~33.6 MB

    unsigned short* wf = (unsigned short*)d_ws;
    const int packN = KVOL * 8 * 64;
    pack_w<<<(packN + 255) / 256, 256, 0, stream>>>(weight, wf);

    if (ws_size >= WF_BYTES + FBF_BYTES) {
        char* fbf = (char*)d_ws + WF_BYTES;
        const int total8 = n * 8;                                  // uint4s of feats
        cvt_feats<<<(total8 + 8 + 255) / 256, 256, 0, stream>>>(feats, (uint4*)fbf, total8);
        spconv_mfma64<<<n / 128, 128, 0, stream>>>(fbf, (const uint4*)wf, bias,
                                                   in_idx, mask, out, n);
    } else {
        spconv_mfma_f32<<<n / 128, 256, 0, stream>>>(feats, wf, bias,
                                                     in_idx, mask, out, n);
    }
}

// Round 8
// 95.442 us; speedup vs baseline: 1.0140x; 1.0140x over previous
//
#include <hip/hip_runtime.h>

#define CIN  64
#define COUT 64
#define KVOL 27

typedef __attribute__((ext_vector_type(8))) short bf16x8;
typedef __attribute__((ext_vector_type(4))) float f32x4;

union U4H8 { uint4 u; bf16x8 h; };

static __device__ __forceinline__ unsigned short f2bf(float x) {
    union { float f; unsigned int u; } v; v.f = x;
    return (unsigned short)((v.u + 0x7FFFu + ((v.u >> 16) & 1u)) >> 16);  // RNE
}

// Re-pack weight[27][64][64] fp32 -> bf16 B-fragment order:
// entry e = (k*8 + kh*4 + ntl)*64 + lane holds 8 bf16 =
//   W[k][32*kh + (lane>>4)*8 + j][16*ntl + (lane&15)]
__global__ __launch_bounds__(256) void pack_w(const float* __restrict__ W,
                                              unsigned short* __restrict__ wf) {
    int t = blockIdx.x * 256 + threadIdx.x;
    if (t >= KVOL * 8 * 64) return;
    int lane  = t & 63;
    int frag  = (t >> 6) & 7;
    int k     = t >> 9;
    int kh    = frag >> 2, nt = frag & 3;
    int col   = nt * 16 + (lane & 15);
    int kbase = kh * 32 + (lane >> 4) * 8;
    const float* src = W + (size_t)k * (CIN * COUT) + (size_t)kbase * COUT + col;
    unsigned int pk[4];
    #pragma unroll
    for (int j = 0; j < 4; ++j) {
        unsigned int lo = f2bf(src[(2 * j) * COUT]);
        unsigned int hi = f2bf(src[(2 * j + 1) * COUT]);
        pk[j] = lo | (hi << 16);
    }
    *reinterpret_cast<uint4*>(wf + (size_t)t * 8) = make_uint4(pk[0], pk[1], pk[2], pk[3]);
}

// feats fp32 [N][64] -> bf16 [N+1][64] (row N = zeros). One thread = 8 elems.
__global__ __launch_bounds__(256) void cvt_feats(const float* __restrict__ f,
                                                 uint4* __restrict__ o, int total8) {
    int t = blockIdx.x * 256 + threadIdx.x;
    if (t < total8) {
        const float4* p = reinterpret_cast<const float4*>(f) + 2 * (size_t)t;
        float4 a = p[0], b = p[1];
        unsigned int u0 = (unsigned int)f2bf(a.x) | ((unsigned int)f2bf(a.y) << 16);
        unsigned int u1 = (unsigned int)f2bf(a.z) | ((unsigned int)f2bf(a.w) << 16);
        unsigned int u2 = (unsigned int)f2bf(b.x) | ((unsigned int)f2bf(b.y) << 16);
        unsigned int u3 = (unsigned int)f2bf(b.z) | ((unsigned int)f2bf(b.w) << 16);
        o[t] = make_uint4(u0, u1, u2, u3);
    } else if (t < total8 + 8) {
        o[t] = make_uint4(0u, 0u, 0u, 0u);   // zero row at index N
    }
}

// Main: 2 waves/block, 64 rows/wave (4 M-tiles x full 64 cols).
// 3-deep A-gather register pipeline: gather issued at iter k is consumed at
// iter k+2 (~2 iters of cover >= worst-case L3 latency). idx/mask 2-slot,
// loaded 4 iters ahead, consumed 2 iters later. Weights reg-staged -> LDS,
// RAW s_barrier (counted vmcnt only, no drain).
__global__ __launch_bounds__(128) void spconv_mfma64(
    const char* __restrict__ fbf,          // (n+1) rows x 128 B bf16
    const uint4* __restrict__ wf4,
    const float* __restrict__ bias,
    const int*   __restrict__ in_idx,
    const float* __restrict__ mask,
    float* __restrict__ out, int n)
{
    const int tid  = threadIdx.x;
    const int lane = tid & 63;
    const int wv   = tid >> 6;
    const int rloc = lane & 15;
    const int grp  = lane >> 4;

    // XCD-aware bijective swizzle (neutral, kept)
    const int nwg = gridDim.x;
    int bid = blockIdx.x;
    if ((nwg & 7) == 0) {
        const int chunk = nwg >> 3;
        bid = (blockIdx.x & 7) * chunk + (blockIdx.x >> 3);
    }
    const int row0 = bid * 128 + wv * 64;

    __shared__ uint4 lds_w[2][512];        // double-buffered B-fragments, 16 KB

    f32x4 acc[4][4];
    #pragma unroll
    for (int nt = 0; nt < 4; ++nt) {
        float b = bias[nt * 16 + rloc];
        f32x4 v = {b, b, b, b};
        acc[0][nt] = v; acc[1][nt] = v; acc[2][nt] = v; acc[3][nt] = v;
    }

    int rowt[4];
    #pragma unroll
    for (int t = 0; t < 4; ++t) rowt[t] = row0 + 16 * t + rloc;

    const unsigned zoff = (unsigned)n * 128u;

    // ---- prologue ----
    // stage w(0) into LDS first; the full drain here covers only w-loads.
    lds_w[0][tid]       = wf4[tid];
    lds_w[0][tid + 128] = wf4[tid + 128];
    lds_w[0][tid + 256] = wf4[tid + 256];
    lds_w[0][tid + 384] = wf4[tid + 384];
    __syncthreads();

    // direct idx/mask for k=0,1; issue their gathers (slots 0,1)
    U4H8 a[3][4][2];
    {
        int i0[4]; float m0[4];
        #pragma unroll
        for (int t = 0; t < 4; ++t) { i0[t] = in_idx[rowt[t]]; m0[t] = mask[rowt[t]]; }
        #pragma unroll
        for (int t = 0; t < 4; ++t) {
            unsigned o = (m0[t] != 0.0f) ? (unsigned)i0[t] * 128u : zoff;
            const uint4* p = reinterpret_cast<const uint4*>(fbf + o) + grp;
            a[0][t][0].u = p[0];
            a[0][t][1].u = p[4];
        }
        #pragma unroll
        for (int t = 0; t < 4; ++t) { i0[t] = in_idx[(size_t)n + rowt[t]]; m0[t] = mask[(size_t)n + rowt[t]]; }
        #pragma unroll
        for (int t = 0; t < 4; ++t) {
            unsigned o = (m0[t] != 0.0f) ? (unsigned)i0[t] * 128u : zoff;
            const uint4* p = reinterpret_cast<const uint4*>(fbf + o) + grp;
            a[1][t][0].u = p[0];
            a[1][t][1].u = p[4];
        }
    }

    // idx(2) -> islot 0, idx(3) -> islot 1
    int idxb[2][4]; float mskb[2][4];
    #pragma unroll
    for (int t = 0; t < 4; ++t) {
        idxb[0][t] = in_idx[(size_t)2 * n + rowt[t]];
        mskb[0][t] = mask[(size_t)2 * n + rowt[t]];
    }
    #pragma unroll
    for (int t = 0; t < 4; ++t) {
        idxb[1][t] = in_idx[(size_t)3 * n + rowt[t]];
        mskb[1][t] = mask[(size_t)3 * n + rowt[t]];
    }

    #pragma unroll
    for (int k = 0; k < KVOL; ++k) {
        const int cur  = k & 1;            // LDS weight buffer for this iter
        const int nxt  = cur ^ 1;
        const int cslot = k % 3;           // A-slot consumed this iter
        const int gslot = (k + 2) % 3;     // A-slot gathered this iter
        const int islot = k & 1;           // idx slot: holds idx(k+2); reload with idx(k+4)

        // 1. weight prefetch for k+1 — oldest vmem ops of the iter, so the
        //    ds_write's counted vmcnt wait leaves younger gathers in flight.
        uint4 w0, w1, w2, w3;
        if (k + 1 < KVOL) {
            const uint4* s = wf4 + (size_t)(k + 1) * 512;
            w0 = s[tid]; w1 = s[tid + 128]; w2 = s[tid + 256]; w3 = s[tid + 384];
        }

        // 2.+3. A-gathers for k+2 (idx loaded 2 iters ago)
        if (k + 2 < KVOL) {
            #pragma unroll
            for (int t = 0; t < 4; ++t) {
                unsigned o = (mskb[islot][t] != 0.0f) ? (unsigned)idxb[islot][t] * 128u : zoff;
                const uint4* p = reinterpret_cast<const uint4*>(fbf + o) + grp;
                a[gslot][t][0].u = p[0];
                a[gslot][t][1].u = p[4];
            }
        }

        // 4. idx/mask for k+4 into the slot just consumed
        if (k + 4 < KVOL) {
            const size_t kb = (size_t)(k + 4) * n;
            #pragma unroll
            for (int t = 0; t < 4; ++t) {
                idxb[islot][t] = in_idx[kb + rowt[t]];
                mskb[islot][t] = mask[kb + rowt[t]];
            }
        }

        // 5. B fragments from LDS
        U4H8 bf[2][4];
        #pragma unroll
        for (int kh = 0; kh < 2; ++kh)
            #pragma unroll
            for (int ntl = 0; ntl < 4; ++ntl)
                bf[kh][ntl].u = lds_w[cur][(kh * 4 + ntl) * 64 + lane];

        // 6. 32 MFMAs on fragments gathered 2 iterations ago
        #pragma unroll
        for (int t = 0; t < 4; ++t)
            #pragma unroll
            for (int ntl = 0; ntl < 4; ++ntl) {
                acc[t][ntl] = __builtin_amdgcn_mfma_f32_16x16x32_bf16(a[cslot][t][0].h, bf[0][ntl].h, acc[t][ntl], 0, 0, 0);
                acc[t][ntl] = __builtin_amdgcn_mfma_f32_16x16x32_bf16(a[cslot][t][1].h, bf[1][ntl].h, acc[t][ntl], 0, 0, 0);
            }

        // 7. publish next weight tile; RAW barrier (no vmcnt drain!)
        if (k + 1 < KVOL) {
            lds_w[nxt][tid]       = w0;
            lds_w[nxt][tid + 128] = w1;
            lds_w[nxt][tid + 256] = w2;
            lds_w[nxt][tid + 384] = w3;
            asm volatile("s_waitcnt lgkmcnt(0)" ::: "memory");
            __builtin_amdgcn_s_barrier();
        }
    }

    // C/D layout: col = lane&15, row = grp*4 + reg
    #pragma unroll
    for (int t = 0; t < 4; ++t)
        #pragma unroll
        for (int ntl = 0; ntl < 4; ++ntl)
            #pragma unroll
            for (int r = 0; r < 4; ++r) {
                int orow = row0 + 16 * t + grp * 4 + r;
                out[(size_t)orow * COUT + ntl * 16 + rloc] = acc[t][ntl][r];
            }
}

// ---- fallback (round-2 kernel): fp32 gather + in-loop cvt, used if ws too small ----
static __device__ __forceinline__ bf16x8 cvt8(float4 a, float4 b, float m) {
    bf16x8 r;
    r[0] = (short)f2bf(a.x * m); r[1] = (short)f2bf(a.y * m);
    r[2] = (short)f2bf(a.z * m); r[3] = (short)f2bf(a.w * m);
    r[4] = (short)f2bf(b.x * m); r[5] = (short)f2bf(b.y * m);
    r[6] = (short)f2bf(b.z * m); r[7] = (short)f2bf(b.w * m);
    return r;
}

__global__ __launch_bounds__(256) void spconv_mfma_f32(
    const float* __restrict__ feats,
    const unsigned short* __restrict__ wf,
    const float* __restrict__ bias,
    const int*   __restrict__ in_idx,
    const float* __restrict__ mask,
    float* __restrict__ out, int n)
{
    const int tid  = threadIdx.x;
    const int lane = tid & 63;
    const int wv   = tid >> 6;
    const int rloc = lane & 15;
    const int grp  = lane >> 4;
    const int row0 = blockIdx.x * 128 + wv * 32;

    __shared__ uint4 lds_w[2][512];

    f32x4 acc[2][4];
    #pragma unroll
    for (int nt = 0; nt < 4; ++nt) {
        float b = bias[nt * 16 + rloc];
        f32x4 v = {b, b, b, b};
        acc[0][nt] = v; acc[1][nt] = v;
    }

    const uint4* wf4 = reinterpret_cast<const uint4*>(wf);
    lds_w[0][tid]       = wf4[tid];
    lds_w[0][tid + 256] = wf4[tid + 256];
    __syncthreads();

    const int rowA = row0 + rloc;
    const int rowB = rowA + 16;

    for (int koff = 0; koff < KVOL; ++koff) {
        const int cur = koff & 1;
        uint4 w0, w1;
        const bool pf = (koff + 1 < KVOL);
        if (pf) {
            const uint4* s = wf4 + (size_t)(koff + 1) * 512;
            w0 = s[tid]; w1 = s[tid + 256];
        }

        const size_t kb = (size_t)koff * n;
        const int   idxA = in_idx[kb + rowA];
        const float mA   = mask[kb + rowA];
        const int   idxB = in_idx[kb + rowB];
        const float mB   = mask[kb + rowB];

        const float4* fA = reinterpret_cast<const float4*>(feats + (size_t)idxA * CIN + grp * 8);
        const float4* fB = reinterpret_cast<const float4*>(feats + (size_t)idxB * CIN + grp * 8);
        float4 a0 = fA[0], a1 = fA[1], a2 = fA[8], a3 = fA[9];
        float4 c0 = fB[0], c1 = fB[1], c2 = fB[8], c3 = fB[9];

        bf16x8 aA0 = cvt8(a0, a1, mA), aA1 = cvt8(a2, a3, mA);
        bf16x8 aB0 = cvt8(c0, c1, mB), aB1 = cvt8(c2, c3, mB);

        U4H8 bf[2][4];
        #pragma unroll
        for (int kh = 0; kh < 2; ++kh)
            #pragma unroll
            for (int nt = 0; nt < 4; ++nt)
                bf[kh][nt].u = lds_w[cur][(kh * 4 + nt) * 64 + lane];

        #pragma unroll
        for (int nt = 0; nt < 4; ++nt) {
            acc[0][nt] = __builtin_amdgcn_mfma_f32_16x16x32_bf16(aA0, bf[0][nt].h, acc[0][nt], 0, 0, 0);
            acc[0][nt] = __builtin_amdgcn_mfma_f32_16x16x32_bf16(aA1, bf[1][nt].h, acc[0][nt], 0, 0, 0);
            acc[1][nt] = __builtin_amdgcn_mfma_f32_16x16x32_bf16(aB0, bf[0][nt].h, acc[1][nt], 0, 0, 0);
            acc[1][nt] = __builtin_amdgcn_mfma_f32_16x16x32_bf16(aB1, bf[1][nt].h, acc[1][nt], 0, 0, 0);
        }

        if (pf) {
            lds_w[cur ^ 1][tid]       = w0;
            lds_w[cur ^ 1][tid + 256] = w1;
        }
        __syncthreads();
    }

    #pragma unroll
    for (int t = 0; t < 2; ++t)
        #pragma unroll
        for (int nt = 0; nt < 4; ++nt)
            #pragma unroll
            for (int r = 0; r < 4; ++r) {
                int orow = row0 + t * 16 + grp * 4 + r;
                out[(size_t)orow * COUT + nt * 16 + rloc] = acc[t][nt][r];
            }
}

extern "C" void kernel_launch(void* const* d_in, const int* in_sizes, int n_in,
                              void* d_out, int out_size, void* d_ws, size_t ws_size,
                              hipStream_t stream)
{
    const float* feats  = (const float*)d_in[0];
    const float* weight = (const float*)d_in[1];
    const float* bias   = (const float*)d_in[2];
    const int*   in_idx = (const int*)  d_in[3];
    // d_in[4] = out_idx (unused: out_idx[k][i] == i where mask==1)
    const float* mask   = (const float*)d_in[5];
    float* out = (float*)d_out;

    const int n = in_sizes[0] / CIN;  // 262144

    const size_t WF_BYTES  = (size_t)KVOL * 8 * 64 * 16;          // 221184
    const size_t FBF_BYTES = (size_t)(n + 1) * CIN * 2;           // ~33.6 MB

    unsigned short* wf = (unsigned short*)d_ws;
    const int packN = KVOL * 8 * 64;
    pack_w<<<(packN + 255) / 256, 256, 0, stream>>>(weight, wf);

    if (ws_size >= WF_BYTES + FBF_BYTES) {
        char* fbf = (char*)d_ws + WF_BYTES;
        const int total8 = n * 8;                                  // uint4s of feats
        cvt_feats<<<(total8 + 8 + 255) / 256, 256, 0, stream>>>(feats, (uint4*)fbf, total8);
        spconv_mfma64<<<n / 128, 128, 0, stream>>>(fbf, (const uint4*)wf, bias,
                                                   in_idx, mask, out, n);
    } else {
        spconv_mfma_f32<<<n / 128, 256, 0, stream>>>(feats, wf, bias,
                                                     in_idx, mask, out, n);
    }
}

// Round 9
// 87.441 us; speedup vs baseline: 1.1068x; 1.0915x over previous
//
#include <hip/hip_runtime.h>

#define CIN  64
#define COUT 64
#define KVOL 27

typedef __attribute__((ext_vector_type(8))) short bf16x8;
typedef __attribute__((ext_vector_type(4))) float f32x4;

union U4H8 { uint4 u; bf16x8 h; };

static __device__ __forceinline__ unsigned short f2bf(float x) {
    union { float f; unsigned int u; } v; v.f = x;
    return (unsigned short)((v.u + 0x7FFFu + ((v.u >> 16) & 1u)) >> 16);  // RNE
}

// Re-pack weight[27][64][64] fp32 -> bf16 B-fragment order:
// entry e = (k*8 + kh*4 + ntl)*64 + lane holds 8 bf16 =
//   W[k][32*kh + (lane>>4)*8 + j][16*ntl + (lane&15)]
__global__ __launch_bounds__(256) void pack_w(const float* __restrict__ W,
                                              unsigned short* __restrict__ wf) {
    int t = blockIdx.x * 256 + threadIdx.x;
    if (t >= KVOL * 8 * 64) return;
    int lane  = t & 63;
    int frag  = (t >> 6) & 7;
    int k     = t >> 9;
    int kh    = frag >> 2, nt = frag & 3;
    int col   = nt * 16 + (lane & 15);
    int kbase = kh * 32 + (lane >> 4) * 8;
    const float* src = W + (size_t)k * (CIN * COUT) + (size_t)kbase * COUT + col;
    unsigned int pk[4];
    #pragma unroll
    for (int j = 0; j < 4; ++j) {
        unsigned int lo = f2bf(src[(2 * j) * COUT]);
        unsigned int hi = f2bf(src[(2 * j + 1) * COUT]);
        pk[j] = lo | (hi << 16);
    }
    *reinterpret_cast<uint4*>(wf + (size_t)t * 8) = make_uint4(pk[0], pk[1], pk[2], pk[3]);
}

// feats fp32 [N][64] -> bf16 [N+1][64] (row N = zeros). One thread = 8 elems.
__global__ __launch_bounds__(256) void cvt_feats(const float* __restrict__ f,
                                                 uint4* __restrict__ o, int total8) {
    int t = blockIdx.x * 256 + threadIdx.x;
    if (t < total8) {
        const float4* p = reinterpret_cast<const float4*>(f) + 2 * (size_t)t;
        float4 a = p[0], b = p[1];
        unsigned int u0 = (unsigned int)f2bf(a.x) | ((unsigned int)f2bf(a.y) << 16);
        unsigned int u1 = (unsigned int)f2bf(a.z) | ((unsigned int)f2bf(a.w) << 16);
        unsigned int u2 = (unsigned int)f2bf(b.x) | ((unsigned int)f2bf(b.y) << 16);
        unsigned int u3 = (unsigned int)f2bf(b.z) | ((unsigned int)f2bf(b.w) << 16);
        o[t] = make_uint4(u0, u1, u2, u3);
    } else if (t < total8 + 8) {
        o[t] = make_uint4(0u, 0u, 0u, 0u);   // zero row at index N
    }
}

// Main: 4 waves/block, 64 rows/wave (256 rows/block) -> TLP: 4 blocks/CU
// x 4 waves fills all SIMDs. Per-wave structure identical to the proven
// round-6 kernel: reg-staged weights -> LDS dbuf, RAW s_barrier (counted
// vmcnt only), 3-slot A-gather pipeline, invalid pairs gather zero row.
__global__ __launch_bounds__(256) void spconv_mfma64(
    const char* __restrict__ fbf,          // (n+1) rows x 128 B bf16
    const uint4* __restrict__ wf4,
    const float* __restrict__ bias,
    const int*   __restrict__ in_idx,
    const float* __restrict__ mask,
    float* __restrict__ out, int n)
{
    const int tid  = threadIdx.x;
    const int lane = tid & 63;
    const int wv   = tid >> 6;
    const int rloc = lane & 15;
    const int grp  = lane >> 4;

    // XCD-aware bijective swizzle (neutral, kept)
    const int nwg = gridDim.x;
    int bid = blockIdx.x;
    if ((nwg & 7) == 0) {
        const int chunk = nwg >> 3;
        bid = (blockIdx.x & 7) * chunk + (blockIdx.x >> 3);
    }
    const int row0 = bid * 256 + wv * 64;

    __shared__ uint4 lds_w[2][512];        // double-buffered B-fragments, 16 KB

    f32x4 acc[4][4];
    #pragma unroll
    for (int nt = 0; nt < 4; ++nt) {
        float b = bias[nt * 16 + rloc];
        f32x4 v = {b, b, b, b};
        acc[0][nt] = v; acc[1][nt] = v; acc[2][nt] = v; acc[3][nt] = v;
    }

    int rowt[4];
    #pragma unroll
    for (int t = 0; t < 4; ++t) rowt[t] = row0 + 16 * t + rloc;

    const unsigned zoff = (unsigned)n * 128u;

    // ---- prologue ----
    // stage w(0) into LDS first; the full drain here covers only w-loads.
    lds_w[0][tid]       = wf4[tid];
    lds_w[0][tid + 256] = wf4[tid + 256];
    __syncthreads();

    // direct idx/mask for k=0,1; issue their gathers (slots 0,1)
    U4H8 a[3][4][2];
    {
        int i0[4]; float m0[4];
        #pragma unroll
        for (int t = 0; t < 4; ++t) { i0[t] = in_idx[rowt[t]]; m0[t] = mask[rowt[t]]; }
        #pragma unroll
        for (int t = 0; t < 4; ++t) {
            unsigned o = (m0[t] != 0.0f) ? (unsigned)i0[t] * 128u : zoff;
            const uint4* p = reinterpret_cast<const uint4*>(fbf + o) + grp;
            a[0][t][0].u = p[0];
            a[0][t][1].u = p[4];
        }
        #pragma unroll
        for (int t = 0; t < 4; ++t) { i0[t] = in_idx[(size_t)n + rowt[t]]; m0[t] = mask[(size_t)n + rowt[t]]; }
        #pragma unroll
        for (int t = 0; t < 4; ++t) {
            unsigned o = (m0[t] != 0.0f) ? (unsigned)i0[t] * 128u : zoff;
            const uint4* p = reinterpret_cast<const uint4*>(fbf + o) + grp;
            a[1][t][0].u = p[0];
            a[1][t][1].u = p[4];
        }
    }

    // idx(2) -> islot 0, idx(3) -> islot 1
    int idxb[2][4]; float mskb[2][4];
    #pragma unroll
    for (int t = 0; t < 4; ++t) {
        idxb[0][t] = in_idx[(size_t)2 * n + rowt[t]];
        mskb[0][t] = mask[(size_t)2 * n + rowt[t]];
    }
    #pragma unroll
    for (int t = 0; t < 4; ++t) {
        idxb[1][t] = in_idx[(size_t)3 * n + rowt[t]];
        mskb[1][t] = mask[(size_t)3 * n + rowt[t]];
    }

    #pragma unroll
    for (int k = 0; k < KVOL; ++k) {
        const int cur  = k & 1;            // LDS weight buffer for this iter
        const int nxt  = cur ^ 1;
        const int cslot = k % 3;           // A-slot consumed this iter
        const int gslot = (k + 2) % 3;     // A-slot gathered this iter
        const int islot = k & 1;           // idx slot: holds idx(k+2); reload with idx(k+4)

        // 1. weight prefetch for k+1 — oldest vmem ops of the iter, so the
        //    ds_write's counted vmcnt wait leaves younger gathers in flight.
        uint4 w0, w1;
        if (k + 1 < KVOL) {
            const uint4* s = wf4 + (size_t)(k + 1) * 512;
            w0 = s[tid]; w1 = s[tid + 256];
        }

        // 2. A-gathers for k+2 (idx loaded 2 iters ago)
        if (k + 2 < KVOL) {
            #pragma unroll
            for (int t = 0; t < 4; ++t) {
                unsigned o = (mskb[islot][t] != 0.0f) ? (unsigned)idxb[islot][t] * 128u : zoff;
                const uint4* p = reinterpret_cast<const uint4*>(fbf + o) + grp;
                a[gslot][t][0].u = p[0];
                a[gslot][t][1].u = p[4];
            }
        }

        // 3. idx/mask for k+4 into the slot just consumed
        if (k + 4 < KVOL) {
            const size_t kb = (size_t)(k + 4) * n;
            #pragma unroll
            for (int t = 0; t < 4; ++t) {
                idxb[islot][t] = in_idx[kb + rowt[t]];
                mskb[islot][t] = mask[kb + rowt[t]];
            }
        }

        // discourage the scheduler from sinking the gather issue below
        __builtin_amdgcn_sched_barrier(0);

        // 4. B fragments from LDS
        U4H8 bf[2][4];
        #pragma unroll
        for (int kh = 0; kh < 2; ++kh)
            #pragma unroll
            for (int ntl = 0; ntl < 4; ++ntl)
                bf[kh][ntl].u = lds_w[cur][(kh * 4 + ntl) * 64 + lane];

        // 5. 32 MFMAs on fragments gathered 2 iterations ago
        #pragma unroll
        for (int t = 0; t < 4; ++t)
            #pragma unroll
            for (int ntl = 0; ntl < 4; ++ntl) {
                acc[t][ntl] = __builtin_amdgcn_mfma_f32_16x16x32_bf16(a[cslot][t][0].h, bf[0][ntl].h, acc[t][ntl], 0, 0, 0);
                acc[t][ntl] = __builtin_amdgcn_mfma_f32_16x16x32_bf16(a[cslot][t][1].h, bf[1][ntl].h, acc[t][ntl], 0, 0, 0);
            }

        // 6. publish next weight tile; RAW barrier (no vmcnt drain!)
        if (k + 1 < KVOL) {
            lds_w[nxt][tid]       = w0;
            lds_w[nxt][tid + 256] = w1;
            asm volatile("s_waitcnt lgkmcnt(0)" ::: "memory");
            __builtin_amdgcn_s_barrier();
        }
    }

    // C/D layout: col = lane&15, row = grp*4 + reg
    #pragma unroll
    for (int t = 0; t < 4; ++t)
        #pragma unroll
        for (int ntl = 0; ntl < 4; ++ntl)
            #pragma unroll
            for (int r = 0; r < 4; ++r) {
                int orow = row0 + 16 * t + grp * 4 + r;
                out[(size_t)orow * COUT + ntl * 16 + rloc] = acc[t][ntl][r];
            }
}

// ---- fallback (round-2 kernel): fp32 gather + in-loop cvt, used if ws too small ----
static __device__ __forceinline__ bf16x8 cvt8(float4 a, float4 b, float m) {
    bf16x8 r;
    r[0] = (short)f2bf(a.x * m); r[1] = (short)f2bf(a.y * m);
    r[2] = (short)f2bf(a.z * m); r[3] = (short)f2bf(a.w * m);
    r[4] = (short)f2bf(b.x * m); r[5] = (short)f2bf(b.y * m);
    r[6] = (short)f2bf(b.z * m); r[7] = (short)f2bf(b.w * m);
    return r;
}

__global__ __launch_bounds__(256) void spconv_mfma_f32(
    const float* __restrict__ feats,
    const unsigned short* __restrict__ wf,
    const float* __restrict__ bias,
    const int*   __restrict__ in_idx,
    const float* __restrict__ mask,
    float* __restrict__ out, int n)
{
    const int tid  = threadIdx.x;
    const int lane = tid & 63;
    const int wv   = tid >> 6;
    const int rloc = lane & 15;
    const int grp  = lane >> 4;
    const int row0 = blockIdx.x * 128 + wv * 32;

    __shared__ uint4 lds_w[2][512];

    f32x4 acc[2][4];
    #pragma unroll
    for (int nt = 0; nt < 4; ++nt) {
        float b = bias[nt * 16 + rloc];
        f32x4 v = {b, b, b, b};
        acc[0][nt] = v; acc[1][nt] = v;
    }

    const uint4* wf4 = reinterpret_cast<const uint4*>(wf);
    lds_w[0][tid]       = wf4[tid];
    lds_w[0][tid + 256] = wf4[tid + 256];
    __syncthreads();

    const int rowA = row0 + rloc;
    const int rowB = rowA + 16;

    for (int koff = 0; koff < KVOL; ++koff) {
        const int cur = koff & 1;
        uint4 w0, w1;
        const bool pf = (koff + 1 < KVOL);
        if (pf) {
            const uint4* s = wf4 + (size_t)(koff + 1) * 512;
            w0 = s[tid]; w1 = s[tid + 256];
        }

        const size_t kb = (size_t)koff * n;
        const int   idxA = in_idx[kb + rowA];
        const float mA   = mask[kb + rowA];
        const int   idxB = in_idx[kb + rowB];
        const float mB   = mask[kb + rowB];

        const float4* fA = reinterpret_cast<const float4*>(feats + (size_t)idxA * CIN + grp * 8);
        const float4* fB = reinterpret_cast<const float4*>(feats + (size_t)idxB * CIN + grp * 8);
        float4 a0 = fA[0], a1 = fA[1], a2 = fA[8], a3 = fA[9];
        float4 c0 = fB[0], c1 = fB[1], c2 = fB[8], c3 = fB[9];

        bf16x8 aA0 = cvt8(a0, a1, mA), aA1 = cvt8(a2, a3, mA);
        bf16x8 aB0 = cvt8(c0, c1, mB), aB1 = cvt8(c2, c3, mB);

        U4H8 bf[2][4];
        #pragma unroll
        for (int kh = 0; kh < 2; ++kh)
            #pragma unroll
            for (int nt = 0; nt < 4; ++nt)
                bf[kh][nt].u = lds_w[cur][(kh * 4 + nt) * 64 + lane];

        #pragma unroll
        for (int nt = 0; nt < 4; ++nt) {
            acc[0][nt] = __builtin_amdgcn_mfma_f32_16x16x32_bf16(aA0, bf[0][nt].h, acc[0][nt], 0, 0, 0);
            acc[0][nt] = __builtin_amdgcn_mfma_f32_16x16x32_bf16(aA1, bf[1][nt].h, acc[0][nt], 0, 0, 0);
            acc[1][nt] = __builtin_amdgcn_mfma_f32_16x16x32_bf16(aB0, bf[0][nt].h, acc[1][nt], 0, 0, 0);
            acc[1][nt] = __builtin_amdgcn_mfma_f32_16x16x32_bf16(aB1, bf[1][nt].h, acc[1][nt], 0, 0, 0);
        }

        if (pf) {
            lds_w[cur ^ 1][tid]       = w0;
            lds_w[cur ^ 1][tid + 256] = w1;
        }
        __syncthreads();
    }

    #pragma unroll
    for (int t = 0; t < 2; ++t)
        #pragma unroll
        for (int nt = 0; nt < 4; ++nt)
            #pragma unroll
            for (int r = 0; r < 4; ++r) {
                int orow = row0 + t * 16 + grp * 4 + r;
                out[(size_t)orow * COUT + nt * 16 + rloc] = acc[t][nt][r];
            }
}

extern "C" void kernel_launch(void* const* d_in, const int* in_sizes, int n_in,
                              void* d_out, int out_size, void* d_ws, size_t ws_size,
                              hipStream_t stream)
{
    const float* feats  = (const float*)d_in[0];
    const float* weight = (const float*)d_in[1];
    const float* bias   = (const float*)d_in[2];
    const int*   in_idx = (const int*)  d_in[3];
    // d_in[4] = out_idx (unused: out_idx[k][i] == i where mask==1)
    const float* mask   = (const float*)d_in[5];
    float* out = (float*)d_out;

    const int n = in_sizes[0] / CIN;  // 262144

    const size_t WF_BYTES  = (size_t)KVOL * 8 * 64 * 16;          // 221184
    const size_t FBF_BYTES = (size_t)(n + 1) * CIN * 2;           // ~33.6 MB

    unsigned short* wf = (unsigned short*)d_ws;
    const int packN = KVOL * 8 * 64;
    pack_w<<<(packN + 255) / 256, 256, 0, stream>>>(weight, wf);

    if (ws_size >= WF_BYTES + FBF_BYTES) {
        char* fbf = (char*)d_ws + WF_BYTES;
        const int total8 = n * 8;                                  // uint4s of feats
        cvt_feats<<<(total8 + 8 + 255) / 256, 256, 0, stream>>>(feats, (uint4*)fbf, total8);
        spconv_mfma64<<<n / 256, 256, 0, stream>>>(fbf, (const uint4*)wf, bias,
                                                   in_idx, mask, out, n);
    } else {
        spconv_mfma_f32<<<n / 128, 256, 0, stream>>>(feats, wf, bias,
                                                     in_idx, mask, out, n);
    }
}